// Round 1
// baseline (1024.141 us; speedup 1.0000x reference)
//
#include <hip/hip_runtime.h>
#include <math.h>

#define N_   64
#define CIN  64
#define T_   256
#define V_   17
#define OUT_ 128
#define KS   3
#define TV   4352   // T_*V_
#define VV   289    // V_*V_

static __device__ __forceinline__ int rf(int x){ return __builtin_amdgcn_readfirstlane(x); }

// ---------------- K1: xbar[n,c,v] = mean_t x0[n,c,t,v] ----------------
__global__ void k1_pool(const float* __restrict__ x0, float* __restrict__ xbar){
  int bid = blockIdx.x;            // n*64+c
  int v = threadIdx.x;             // 0..16
  int i = threadIdx.y;             // 0..14
  const float* plane = x0 + (size_t)bid*TV;
  float s = 0.f;
  for(int t=i; t<T_; t+=15) s += plane[t*V_+v];
  __shared__ float red[15*17];
  red[i*17+v] = s;
  __syncthreads();
  if(i==0){
    float tot=0.f;
    #pragma unroll
    for(int ii=0; ii<15; ++ii) tot += red[ii*17+v];
    xbar[bid*V_+v] = tot*(1.f/(float)T_);
  }
}

// ---------------- K2a: weight prep (n-independent) ----------------
__global__ void k2a_prep(const float* __restrict__ conv_w, const float* __restrict__ conv_b,
                         const float* __restrict__ down_w,
                         const float* __restrict__ A_GEME, const float* __restrict__ A_SE,
                         float* __restrict__ convwT, float* __restrict__ Wq, float* __restrict__ Wk,
                         float* __restrict__ bq, float* __restrict__ bk, float* __restrict__ Atile){
  int tid = threadIdx.x;
  // transposed combined weights: convwT[ci][r], r<384 -> conv rows, r>=384 -> down rows
  for(int idx=tid; idx<CIN*512; idx+=256){
    int ci = idx>>9, r = idx&511;
    convwT[idx] = (r<384)? conv_w[r*CIN+ci] : down_w[(r-384)*CIN+ci];
  }
  // pooled conv_w rows for Q (channels 0..15 of quarter) and K (16..31)
  for(int idx=tid; idx<12*CIN; idx+=256){
    int kq = idx>>6, ci = idx&63;
    int k = kq>>2, qq = kq&3;
    int base = k*128 + qq*32;
    float sq=0.f, sk=0.f;
    for(int o=0;o<16;++o){ sq += conv_w[(base+o)*CIN+ci]; sk += conv_w[(base+16+o)*CIN+ci]; }
    Wq[idx] = sq*(1.f/16.f); Wk[idx] = sk*(1.f/16.f);
  }
  if(tid<12){
    int k = tid>>2, qq = tid&3; int base = k*128+qq*32;
    float sq=0.f, sk=0.f;
    for(int o=0;o<16;++o){ sq += conv_b[base+o]; sk += conv_b[base+16+o]; }
    bq[tid]=sq*(1.f/16.f); bk[tid]=sk*(1.f/16.f);
  }
  for(int idx=tid; idx<KS*8*VV; idx+=256) Atile[idx] = A_SE[idx]+A_GEME[idx];
}

// ---------------- K2b: per-n attention -> atten_half[n][k][qq][v][w] ----------------
__global__ __launch_bounds__(256) void k2b_atten(
    const float* __restrict__ xbar,
    const float* __restrict__ Wq, const float* __restrict__ Wk,
    const float* __restrict__ bq, const float* __restrict__ bk,
    const float* __restrict__ W_spa, const float* __restrict__ b_spa,
    const float* __restrict__ W_mix, const float* __restrict__ b_mix,
    float* __restrict__ attenh){
  __shared__ float xb[CIN*V_];
  __shared__ float lWq[12*CIN], lWk[12*CIN], lbq[12], lbk[12];
  __shared__ float lWs[VV], lbs[V_], lWm[VV], lbm[V_];
  __shared__ float Qb[12*V_], Kb[12*V_], Qs[12*V_], Ks_[12*V_], Km[12*V_], Qm[12*V_];
  __shared__ float Sb[12*VV], Cb[9*VV];
  int tid = threadIdx.x;
  int n = blockIdx.x;
  for(int i=tid;i<CIN*V_;i+=256) xb[i]=xbar[n*CIN*V_+i];
  for(int i=tid;i<12*CIN;i+=256){ lWq[i]=Wq[i]; lWk[i]=Wk[i]; }
  if(tid<12){ lbq[tid]=bq[tid]; lbk[tid]=bk[tid]; }
  for(int i=tid;i<VV;i+=256){ lWs[i]=W_spa[i]; lWm[i]=W_mix[i]; }
  if(tid<V_){ lbs[tid]=b_spa[tid]; lbm[tid]=b_mix[tid]; }
  __syncthreads();
  // Q/K pooled features
  if(tid<204){
    int kq=tid/17, v=tid%17;
    float qv=lbq[kq], kv=lbk[kq];
    for(int ci=0;ci<CIN;++ci){
      float xv = xb[ci*V_+v];
      qv += lWq[kq*CIN+ci]*xv;
      kv += lWk[kq*CIN+ci]*xv;
    }
    Qb[tid]=qv; Kb[tid]=kv;
  }
  __syncthreads();
  // linear + relu (Spa and Mix)
  if(tid<204){
    int kq=tid/17, v=tid%17;
    float qs=lbs[v], ks=lbs[v], km=lbm[v], qm=lbm[v];
    #pragma unroll
    for(int u=0;u<V_;++u){
      float ws = lWs[v*V_+u], wm = lWm[v*V_+u];
      float qbu = Qb[kq*V_+u], kbu = Kb[kq*V_+u];
      qs += ws*qbu;
      ks += ws*kbu;
      km += wm*kbu;
      qm += wm*qbu;
    }
    Qs[tid]=fmaxf(qs,0.f); Ks_[tid]=fmaxf(ks,0.f); Km[tid]=fmaxf(km,0.f); Qm[tid]=fmaxf(qm,0.f);
  }
  __syncthreads();
  // S rows, stored scaled by 0.25 (atten_half = S/4 + cross/8)
  if(tid<204){
    int kq=tid/17, v=tid%17;
    float a=Qs[tid];
    float e[17]; float mx=-1e30f;
    #pragma unroll
    for(int w=0;w<V_;++w){ e[w]=a*Ks_[kq*V_+w]; mx=fmaxf(mx,e[w]); }
    float s=0.f;
    #pragma unroll
    for(int w=0;w<V_;++w){ e[w]=expf(e[w]-mx); s+=e[w]; }
    float inv=0.25f/s;
    #pragma unroll
    for(int w=0;w<V_;++w) Sb[kq*VV+v*V_+w]=e[w]*inv;
  }
  __syncthreads();
  // cross rows, stored scaled by 0.125
  if(tid<153){
    int kj=tid/17, v=tid%17;
    int k=kj/3, j=kj%3;
    float a=Km[(k*4+j)*V_+v];
    float e[17]; float mx=-1e30f;
    #pragma unroll
    for(int w=0;w<V_;++w){ e[w]=a*Qm[(k*4+j+1)*V_+w]; mx=fmaxf(mx,e[w]); }
    float s=0.f;
    #pragma unroll
    for(int w=0;w<V_;++w){ e[w]=expf(e[w]-mx); s+=e[w]; }
    float inv=0.125f/s;
    #pragma unroll
    for(int w=0;w<V_;++w) Cb[kj*VV+v*V_+w]=e[w]*inv;
  }
  __syncthreads();
  // combine quarters: atten_half
  for(int idx=tid; idx<KS*4*VV; idx+=256){
    int kq=idx/VV, rem=idx%VV;
    int k=kq>>2, qq=kq&3;
    float val=Sb[idx];
    if(qq>0) val += Cb[(k*3+qq-1)*VV+rem];
    if(qq<3) val += Cb[(k*3+qq)*VV+rem];
    attenh[(size_t)n*(KS*4*VV)+idx]=val;
  }
}

// ---------------- K3: fused conv + graph conv + stats ----------------
// block = (t-chunk of 4, n); 256 threads
__global__ __launch_bounds__(256) void k3_main(
    const float* __restrict__ x0, const float* __restrict__ convwT,
    const float* __restrict__ conv_b, const float* __restrict__ down_b,
    const float* __restrict__ attenh, const float* __restrict__ Atile,
    float* __restrict__ mout,          // d_out used as scratch for m_out
    float* __restrict__ s1ws, float* __restrict__ s2ws,
    float* __restrict__ dSws, float* __restrict__ dSSws){
  __shared__ float mt[128*80];                  // [c][t(4)][20pad]
  __shared__ float s1c[128], s2c[128], dS[128], dSS[128];
  int tid = threadIdx.x;
  int chunk = blockIdx.x, n = blockIdx.y;
  int t0 = chunk*4;
  int c  = tid & 127;                 // conv-phase channel
  int th = rf(tid>>7);                // conv-phase t-half (wave-uniform)
  int lane = tid & 63;
  int wvid = rf(tid>>6) & 3;          // wave id
  int tln = lane & 3;                 // graph-phase t
  int jln = lane >> 2;                // graph-phase 0..15

  if(tid<128){ s1c[tid]=0.f; s2c[tid]=0.f; dS[tid]=0.f; dSS[tid]=0.f; }
  __syncthreads();

  // ---- down-path stats (values recomputed in K5) ----
  {
    float acc[2][17];
    float b = down_b[c];
    #pragma unroll
    for(int tl=0;tl<2;++tl)
      #pragma unroll
      for(int v=0;v<V_;++v) acc[tl][v]=b;
    for(int ci=0; ci<CIN; ++ci){
      float wv = convwT[ci*512 + 384 + c];
      const float* xc = x0 + (size_t)((n*CIN+ci)*T_ + t0 + th*2)*V_;  // uniform -> s_load
      #pragma unroll
      for(int tl=0;tl<2;++tl)
        #pragma unroll
        for(int v=0;v<V_;++v) acc[tl][v] += wv*xc[tl*V_+v];
    }
    float s=0.f, ss=0.f;
    #pragma unroll
    for(int tl=0;tl<2;++tl)
      #pragma unroll
      for(int v=0;v<V_;++v){ float a=acc[tl][v]; s+=a; ss+=a*a; }
    atomicAdd(&dS[c], s); atomicAdd(&dSS[c], ss);
  }
  __syncthreads();
  if(tid<128){ atomicAdd(&dSws[tid], dS[tid]); atomicAdd(&dSSws[tid], dSS[tid]); }

  // ---- conv + graph, k = 0..2 ----
  float p1[2][17], p2[2][17];
  #pragma unroll
  for(int a=0;a<2;++a)
    #pragma unroll
    for(int w=0;w<V_;++w){ p1[a][w]=0.f; p2[a][w]=0.f; }

  for(int kk=0; kk<KS; ++kk){
    float acc[2][17];
    float b = conv_b[kk*128 + c];
    #pragma unroll
    for(int tl=0;tl<2;++tl)
      #pragma unroll
      for(int v=0;v<V_;++v) acc[tl][v]=b;
    for(int ci=0; ci<CIN; ++ci){
      float wv = convwT[ci*512 + kk*128 + c];   // coalesced across lanes
      const float* xc = x0 + (size_t)((n*CIN+ci)*T_ + t0 + th*2)*V_;  // uniform -> s_load
      #pragma unroll
      for(int tl=0;tl<2;++tl)
        #pragma unroll
        for(int v=0;v<V_;++v) acc[tl][v] += wv*xc[tl*V_+v];
    }
    __syncthreads();   // previous graph phase done reading mt
    #pragma unroll
    for(int tl=0;tl<2;++tl)
      #pragma unroll
      for(int v=0;v<V_;++v) mt[c*80 + (th*2+tl)*20 + v] = acc[tl][v];
    __syncthreads();
    // P1: atten part; wave-uniform quarter -> SGPR matrix
    {
      const float* ap = attenh + ((size_t)n*KS + kk)*(4*VV) + wvid*VV;
      #pragma unroll
      for(int is=0; is<2; ++is){
        int cc = wvid*32 + is*16 + jln;
        float mr[17];
        #pragma unroll
        for(int v=0;v<V_;++v) mr[v] = mt[cc*80 + tln*20 + v];
        #pragma unroll
        for(int v=0;v<V_;++v){
          float mv = mr[v];
          #pragma unroll
          for(int w=0;w<V_;++w) p1[is][w] += mv*ap[v*V_+w];
        }
      }
    }
    // P2: A_tiled part; wave-uniform group -> SGPR matrix
    {
      #pragma unroll
      for(int gs=0; gs<2; ++gs){
        int g = wvid + gs*4;
        const float* tp = Atile + (kk*8+g)*VV;
        int cc = g + 8*jln;
        float mr[17];
        #pragma unroll
        for(int v=0;v<V_;++v) mr[v] = mt[cc*80 + tln*20 + v];
        #pragma unroll
        for(int v=0;v<V_;++v){
          float mv = mr[v];
          #pragma unroll
          for(int w=0;w<V_;++w) p2[gs][w] += mv*tp[v*V_+w];
        }
      }
    }
  }
  __syncthreads();
  // P1 partials -> mt
  #pragma unroll
  for(int is=0; is<2; ++is){
    int cc = wvid*32 + is*16 + jln;
    #pragma unroll
    for(int w=0;w<V_;++w) mt[cc*80 + tln*20 + w] = p1[is][w];
  }
  __syncthreads();
  // P2 combine + per-(n,c) moments
  #pragma unroll
  for(int gs=0; gs<2; ++gs){
    int cc = wvid + gs*4 + 8*jln;
    float s=0.f, ss=0.f;
    #pragma unroll
    for(int w=0;w<V_;++w){
      float val = mt[cc*80 + tln*20 + w] + p2[gs][w];
      mt[cc*80 + tln*20 + w] = val;
      s += val; ss += val*val;
    }
    atomicAdd(&s1c[cc], s); atomicAdd(&s2c[cc], ss);
  }
  __syncthreads();
  if(tid<128){ atomicAdd(&s1ws[n*128+tid], s1c[tid]); atomicAdd(&s2ws[n*128+tid], s2c[tid]); }
  // coalesced m_out write
  for(int idx=tid; idx<128*68; idx+=256){
    int cc = idx/68, r = idx%68;
    int t = r/17, w = r%17;
    mout[(size_t)(n*128+cc)*TV + t0*V_ + r] = mt[cc*80 + t*20 + w];
  }
}

// ---------------- K4: gate + BN coefficient finalize ----------------
__global__ void k4_stats(const float* __restrict__ s1ws, const float* __restrict__ s2ws,
                         const float* __restrict__ dSws, const float* __restrict__ dSSws,
                         const float* __restrict__ charef_w,
                         const float* __restrict__ bn_gamma, const float* __restrict__ bn_beta,
                         const float* __restrict__ down_bn_gamma, const float* __restrict__ down_bn_beta,
                         float* __restrict__ g1ws, float* __restrict__ coef){
  int c = threadIdx.x;  // 128 threads
  float w0=charef_w[0], w1=charef_w[1], w2=charef_w[2];
  const float invTV = 1.f/(float)TV;
  float Sm=0.f, Sq=0.f;
  for(int n=0;n<N_;++n){
    float s1 = s1ws[n*128+c];
    float cr  = s1*invTV;
    float crm = (c>0)?   s1ws[n*128+c-1]*invTV : 0.f;
    float crp = (c<127)? s1ws[n*128+c+1]*invTV : 0.f;
    float cc = w0*crm + w1*cr + w2*crp;
    float g1 = 1.f + 1.f/(1.f+expf(-cc));   // 1 + sigmoid
    g1ws[n*128+c] = g1;
    Sm += s1*g1;
    Sq += s2ws[n*128+c]*g1*g1;
  }
  const float invNTV = 1.f/((float)N_*(float)TV);
  float mean = Sm*invNTV;
  float var  = Sq*invNTV - mean*mean;
  float sc = bn_gamma[c]*rsqrtf(var+1e-5f);
  coef[c]     = sc;
  coef[128+c] = bn_beta[c] - mean*sc;
  float mD = dSws[c]*invNTV;
  float vD = dSSws[c]*invNTV - mD*mD;
  float scD = down_bn_gamma[c]*rsqrtf(vD+1e-5f);
  coef[256+c] = scD;
  coef[384+c] = down_bn_beta[c] - mD*scD;
}

// ---------------- K5: recompute down, combine BNs, relu ----------------
__global__ __launch_bounds__(256) void k5_out(
    const float* __restrict__ x0, const float* __restrict__ convwT,
    const float* __restrict__ down_b, const float* __restrict__ g1ws,
    const float* __restrict__ coef, float* __restrict__ out){
  __shared__ float mo[128*80];
  int tid=threadIdx.x;
  int chunk=blockIdx.x, n=blockIdx.y;
  int t0=chunk*4;
  int c  = tid&127;
  int th = rf(tid>>7);
  // stage m_out chunk (coalesced)
  for(int idx=tid; idx<128*68; idx+=256){
    int cc=idx/68, r=idx%68;
    int t=r/17, w=r%17;
    mo[cc*80 + t*20 + w] = out[(size_t)(n*128+cc)*TV + t0*V_ + r];
  }
  // recompute down-path values
  float acc[2][17];
  {
    float b = down_b[c];
    #pragma unroll
    for(int tl=0;tl<2;++tl)
      #pragma unroll
      for(int v=0;v<V_;++v) acc[tl][v]=b;
    for(int ci=0; ci<CIN; ++ci){
      float wv = convwT[ci*512 + 384 + c];
      const float* xc = x0 + (size_t)((n*CIN+ci)*T_ + t0 + th*2)*V_;
      #pragma unroll
      for(int tl=0;tl<2;++tl)
        #pragma unroll
        for(int v=0;v<V_;++v) acc[tl][v] += wv*xc[tl*V_+v];
    }
  }
  __syncthreads();
  float sc = coef[c], sh = coef[128+c], scD = coef[256+c], shD = coef[384+c];
  float g1 = g1ws[n*128+c];
  float a1 = sc*g1;
  #pragma unroll
  for(int tl=0;tl<2;++tl){
    #pragma unroll
    for(int v=0;v<V_;++v){
      int li = c*80 + (th*2+tl)*20 + v;
      float r = a1*mo[li] + sh + scD*acc[tl][v] + shD;
      mo[li] = fmaxf(r, 0.f);
    }
  }
  __syncthreads();
  for(int idx=tid; idx<128*68; idx+=256){
    int cc=idx/68, r=idx%68;
    int t=r/17, w=r%17;
    out[(size_t)(n*128+cc)*TV + t0*V_ + r] = mo[cc*80 + t*20 + w];
  }
}

extern "C" void kernel_launch(void* const* d_in, const int* in_sizes, int n_in,
                              void* d_out, int out_size, void* d_ws, size_t ws_size,
                              hipStream_t stream){
  const float* x0      = (const float*)d_in[0];
  const float* conv_w  = (const float*)d_in[1];
  const float* conv_b  = (const float*)d_in[2];
  const float* W_spa   = (const float*)d_in[3];
  const float* b_spa   = (const float*)d_in[4];
  const float* W_mix   = (const float*)d_in[5];
  const float* b_mix   = (const float*)d_in[6];
  const float* A_GEME  = (const float*)d_in[7];
  const float* A_SE    = (const float*)d_in[8];
  const float* charef_w= (const float*)d_in[9];
  const float* bn_gamma= (const float*)d_in[10];
  const float* bn_beta = (const float*)d_in[11];
  const float* down_w  = (const float*)d_in[12];
  const float* down_b  = (const float*)d_in[13];
  const float* down_bn_gamma = (const float*)d_in[14];
  const float* down_bn_beta  = (const float*)d_in[15];
  float* out = (float*)d_out;
  float* ws  = (float*)d_ws;

  float* xbar   = ws;                 // 69632
  float* convwT = xbar + 69632;       // 32768
  float* Wq     = convwT + 32768;     // 768
  float* Wk     = Wq + 768;           // 768
  float* bq     = Wk + 768;           // 12
  float* bk     = bq + 12;            // 12
  float* Atile  = bk + 12;            // 6936
  float* attenh = Atile + 6936;       // 221952
  float* s1ws   = attenh + 221952;    // 8192  -- accumulators (memset region start)
  float* s2ws   = s1ws + 8192;        // 8192
  float* dSws   = s2ws + 8192;        // 128
  float* dSSws  = dSws + 128;         // 128   -- memset region end (16640 floats)
  float* g1ws   = dSSws + 128;        // 8192
  float* coef   = g1ws + 8192;        // 512

  hipMemsetAsync(s1ws, 0, (size_t)16640*sizeof(float), stream);
  k1_pool<<<dim3(N_*CIN), dim3(17,15), 0, stream>>>(x0, xbar);
  k2a_prep<<<1, 256, 0, stream>>>(conv_w, conv_b, down_w, A_GEME, A_SE,
                                  convwT, Wq, Wk, bq, bk, Atile);
  k2b_atten<<<N_, 256, 0, stream>>>(xbar, Wq, Wk, bq, bk, W_spa, b_spa, W_mix, b_mix, attenh);
  k3_main<<<dim3(64, N_), 256, 0, stream>>>(x0, convwT, conv_b, down_b, attenh, Atile,
                                            out, s1ws, s2ws, dSws, dSSws);
  k4_stats<<<1, 128, 0, stream>>>(s1ws, s2ws, dSws, dSSws, charef_w,
                                  bn_gamma, bn_beta, down_bn_gamma, down_bn_beta, g1ws, coef);
  k5_out<<<dim3(64, N_), 256, 0, stream>>>(x0, convwT, down_b, g1ws, coef, out);
}